// Round 6
// baseline (44.131 us; speedup 1.0000x reference)
//
#include <hip/hip_runtime.h>

#define B_  32
#define H_  512
#define W_  512
#define HW_ (H_ * W_)
#define RSTRIP_ 8
#define NBLK_ 1024             // 1024 blocks * 4 waves = 4096 waves = 32 img * 64 strips * 2 halves

__device__ __forceinline__ float rcp_fast(float x) { return __builtin_amdgcn_rcpf(x); }

// WENO3, single fast-rcp form (validated rounds 1-5, absmax 0.0)
__device__ __forceinline__ float weno_minus(float vmm, float vm, float vp) {
    float d0 = vmm - vm, d1 = vm - vp;
    float t0 = 1e-6f + d0 * d0;
    float t1 = 1e-6f + d1 * d1;
    float s0 = t0 * t0, s1 = t1 * t1;
    float s0x2 = s0 + s0;
    float p0 = 1.5f * vm - 0.5f * vmm;
    float p1 = 0.5f * (vm + vp);
    return (s1 * p0 + s0x2 * p1) * rcp_fast(s1 + s0x2);
}

__device__ __forceinline__ float weno_plus(float vmm, float vm, float vp) {
    float d0 = vp - vm, d1 = vm - vmm;
    float t0 = 1e-6f + d0 * d0;
    float t1 = 1e-6f + d1 * d1;
    float s0 = t0 * t0, s1 = t1 * t1;
    float s0x2 = s0 + s0;
    float p0 = 1.5f * vm - 0.5f * vp;
    float p1 = 0.5f * (vm + vmm);
    return (s1 * p0 + s0x2 * p1) * rcp_fast(s1 + s0x2);
}

__device__ __forceinline__ void pixel_eval(
        float vxmm, float vxm, float vxc, float vxp,
        float vymm, float vym, float vyc, float vyp,
        float rh, float target, float lo, float hi,
        float& num, float& den) {
    float ux_minus = weno_minus(vxmm, vxm, vxc);
    float ux_plus  = weno_plus(vxm, vxc, vxp);
    float gx = fmaxf(fmaxf(ux_minus, -ux_plus), 0.0f);

    float uy_minus = weno_minus(vymm, vym, vyc);
    float uy_plus  = weno_plus(vym, vyc, vyp);
    float gy = fmaxf(fmaxf(uy_minus, -uy_plus), 0.0f);

    float gmag = __builtin_amdgcn_sqrtf(gx * gx + gy * gy + 1e-8f);

    float residual = gmag - target;
    float ar = fabsf(residual);
    float per_pixel = (ar < 0.01f) ? (50.0f * residual * residual)
                                   : (ar - 0.005f);

    bool m = (rh > 0.5f) && (gmag >= lo) && (gmag <= hi);
    float sel = m ? 1.0f : 0.0f;
    num = fmaf(sel, per_pixel, num);
    den += sel;
}

__device__ __forceinline__ int clampy(int v) {
    return v < 0 ? 0 : (v > H_ - 1 ? H_ - 1 : v);
}

__global__ __launch_bounds__(256, 4) void eikonal_main(
        const float* __restrict__ pred, const float* __restrict__ reach,
        double2* __restrict__ partials) {
    const float target = 1.0f / sqrtf((float)(511 * 511 + 511 * 511));
    const float lo = 0.3f * target;
    const float hi = 5.0f * target;

    int t = threadIdx.x;
    int lane = t & 63;
    int wv = blockIdx.x * 4 + (t >> 6);   // 0..4095
    int b  = wv >> 7;                     // image
    int r  = wv & 127;
    int s  = r >> 1;                      // strip 0..63
    int h  = r & 1;                       // row half
    int y0 = s * RSTRIP_;
    int x0 = (h << 8) + (lane << 2);      // 4 consecutive px per lane

    const float* base  = pred  + b * HW_ + x0;
    const float* rbase = reach + b * HW_ + x0;
    const float* hbase = pred  + b * HW_;

    bool lane0  = (lane == 0);
    bool lane63 = (lane == 63);
    bool haloL = lane0  && (h == 1);      // needs x = 254,255
    bool haloR = lane63 && (h == 0);      // needs x = 256,257
    bool needs_halo = haloL || haloR;
    int hx = haloL ? 254 : 256;

    // ---- prologue: 6-deep pred rows (y0-2..y0+3), 4-deep halo, 4-deep reach
    float4 pm2 = *(const float4*)(base + (clampy(y0 - 2) << 9));
    float4 pm1 = *(const float4*)(base + (clampy(y0 - 1) << 9));
    float4 p0c = *(const float4*)(base + ((y0    ) << 9));
    float4 pp1 = *(const float4*)(base + ((y0 + 1) << 9));
    float4 pp2 = *(const float4*)(base + ((y0 + 2) << 9));
    float4 pp3 = *(const float4*)(base + ((y0 + 3) << 9));

    float2 h0c = make_float2(0.f, 0.f), h1c = h0c, h2c = h0c, h3c = h0c;
    if (needs_halo) {
        h0c = *(const float2*)(hbase + ((y0    ) << 9) + hx);
        h1c = *(const float2*)(hbase + ((y0 + 1) << 9) + hx);
        h2c = *(const float2*)(hbase + ((y0 + 2) << 9) + hx);
        h3c = *(const float2*)(hbase + ((y0 + 3) << 9) + hx);
    }
    float4 q0 = *(const float4*)(rbase + ((y0    ) << 9));
    float4 q1 = *(const float4*)(rbase + ((y0 + 1) << 9));
    float4 q2 = *(const float4*)(rbase + ((y0 + 2) << 9));
    float4 q3 = *(const float4*)(rbase + ((y0 + 3) << 9));

    float num = 0.0f, den = 0.0f;

    #pragma unroll
    for (int i = 0; i < RSTRIP_; ++i) {
        int y = y0 + i;
        // predicated prefetches: conditions are compile-time after full unroll
        float4 pnew = pp3;
        if (i < 6) pnew = *(const float4*)(base + (clampy(y + 4) << 9));
        float2 hnew = h3c;
        if (needs_halo && i < 4) hnew = *(const float2*)(hbase + ((y + 4) << 9) + hx);
        float4 qnew = q3;
        if (i < 4) qnew = *(const float4*)(rbase + ((y + 4) << 9));

        // x-neighbors via cross-lane shuffle
        float lz = __shfl_up(p0c.z, 1);     // x0-2
        float lw = __shfl_up(p0c.w, 1);     // x0-1
        float rx = __shfl_down(p0c.x, 1);   // x0+4
        float ry = __shfl_down(p0c.y, 1);   // x0+5
        if (lane0)  { lz = (h == 1) ? h0c.x : p0c.x; lw = (h == 1) ? h0c.y : p0c.x; }
        if (lane63) { rx = (h == 0) ? h0c.x : p0c.w; ry = (h == 0) ? h0c.y : p0c.w; }

        float dx0 = lw    - lz;
        float dx1 = p0c.x - lw;
        float dx2 = p0c.y - p0c.x;
        float dx3 = p0c.z - p0c.y;
        float dx4 = p0c.w - p0c.z;
        float dx5 = rx    - p0c.w;
        float dx6 = ry    - rx;

        pixel_eval(dx0, dx1, dx2, dx3,
                   pm1.x - pm2.x, p0c.x - pm1.x, pp1.x - p0c.x, pp2.x - pp1.x,
                   q0.x, target, lo, hi, num, den);
        pixel_eval(dx1, dx2, dx3, dx4,
                   pm1.y - pm2.y, p0c.y - pm1.y, pp1.y - p0c.y, pp2.y - pp1.y,
                   q0.y, target, lo, hi, num, den);
        pixel_eval(dx2, dx3, dx4, dx5,
                   pm1.z - pm2.z, p0c.z - pm1.z, pp1.z - p0c.z, pp2.z - pp1.z,
                   q0.z, target, lo, hi, num, den);
        pixel_eval(dx3, dx4, dx5, dx6,
                   pm1.w - pm2.w, p0c.w - pm1.w, pp1.w - p0c.w, pp2.w - pp1.w,
                   q0.w, target, lo, hi, num, den);

        // roll chains (renamed after full unroll)
        pm2 = pm1; pm1 = p0c; p0c = pp1; pp1 = pp2; pp2 = pp3; pp3 = pnew;
        h0c = h1c; h1c = h2c; h2c = h3c; h3c = hnew;
        q0 = q1; q1 = q2; q2 = q3; q3 = qnew;
    }

    // ---- block reduction ----
    double dn = (double)num;
    double dd = (double)den;
    #pragma unroll
    for (int off = 32; off > 0; off >>= 1) {
        dn += __shfl_down(dn, off);
        dd += __shfl_down(dd, off);
    }
    __shared__ double sn[4], sd[4];
    int wid = t >> 6;
    if (lane == 0) { sn[wid] = dn; sd[wid] = dd; }
    __syncthreads();
    if (t == 0) {
        double2 p;
        p.x = sn[0] + sn[1] + sn[2] + sn[3];
        p.y = sd[0] + sd[1] + sd[2] + sd[3];
        partials[blockIdx.x] = p;
    }
}

__global__ __launch_bounds__(256) void eikonal_finalize(
        const double2* __restrict__ partials, float* __restrict__ out) {
    int t = threadIdx.x;
    double n = 0.0, d = 0.0;
    #pragma unroll
    for (int k = 0; k < NBLK_ / 256; ++k) {
        double2 p = partials[t + (k << 8)];
        n += p.x;
        d += p.y;
    }
    #pragma unroll
    for (int off = 32; off > 0; off >>= 1) {
        n += __shfl_down(n, off);
        d += __shfl_down(d, off);
    }
    __shared__ double sn[4], sd[4];
    int wid = t >> 6;
    int lane = t & 63;
    if (lane == 0) { sn[wid] = n; sd[wid] = d; }
    __syncthreads();
    if (t == 0) {
        double num = sn[0] + sn[1] + sn[2] + sn[3];
        double den = sd[0] + sd[1] + sd[2] + sd[3];
        if (den < 1e-8) den = 1e-8;
        out[0] = (float)(num / den);
    }
}

extern "C" void kernel_launch(void* const* d_in, const int* in_sizes, int n_in,
                              void* d_out, int out_size, void* d_ws, size_t ws_size,
                              hipStream_t stream) {
    const float* pred  = (const float*)d_in[0];
    const float* reach = (const float*)d_in[1];
    float* out = (float*)d_out;
    double2* partials = (double2*)d_ws;   // 1024 * 16B = 16 KB, fully rewritten each call

    eikonal_main<<<NBLK_, 256, 0, stream>>>(pred, reach, partials);
    eikonal_finalize<<<1, 256, 0, stream>>>(partials, out);
}

// Round 7
// 36.700 us; speedup vs baseline: 1.2025x; 1.2025x over previous
//
#include <hip/hip_runtime.h>

#define B_  32
#define H_  512
#define W_  512
#define HW_ (H_ * W_)
#define RSTRIP_ 8
#define NBLK_ 1024             // 1024 blocks * 4 waves = 4096 waves = 32 img * 64 strips * 2 halves

__device__ __forceinline__ float rcp_fast(float x) { return __builtin_amdgcn_rcpf(x); }

// WENO3, single fast-rcp form (validated rounds 1-6, absmax 0.0)
__device__ __forceinline__ float weno_minus(float vmm, float vm, float vp) {
    float d0 = vmm - vm, d1 = vm - vp;
    float t0 = 1e-6f + d0 * d0;
    float t1 = 1e-6f + d1 * d1;
    float s0 = t0 * t0, s1 = t1 * t1;
    float s0x2 = s0 + s0;
    float p0 = 1.5f * vm - 0.5f * vmm;
    float p1 = 0.5f * (vm + vp);
    return (s1 * p0 + s0x2 * p1) * rcp_fast(s1 + s0x2);
}

__device__ __forceinline__ float weno_plus(float vmm, float vm, float vp) {
    float d0 = vp - vm, d1 = vm - vmm;
    float t0 = 1e-6f + d0 * d0;
    float t1 = 1e-6f + d1 * d1;
    float s0 = t0 * t0, s1 = t1 * t1;
    float s0x2 = s0 + s0;
    float p0 = 1.5f * vm - 0.5f * vp;
    float p1 = 0.5f * (vm + vmm);
    return (s1 * p0 + s0x2 * p1) * rcp_fast(s1 + s0x2);
}

__device__ __forceinline__ void pixel_eval(
        float vxmm, float vxm, float vxc, float vxp,
        float vymm, float vym, float vyc, float vyp,
        float rh, float target, float lo, float hi,
        float& num, float& den) {
    float ux_minus = weno_minus(vxmm, vxm, vxc);
    float ux_plus  = weno_plus(vxm, vxc, vxp);
    float gx = fmaxf(fmaxf(ux_minus, -ux_plus), 0.0f);

    float uy_minus = weno_minus(vymm, vym, vyc);
    float uy_plus  = weno_plus(vym, vyc, vyp);
    float gy = fmaxf(fmaxf(uy_minus, -uy_plus), 0.0f);

    float gmag = __builtin_amdgcn_sqrtf(gx * gx + gy * gy + 1e-8f);

    float residual = gmag - target;
    float ar = fabsf(residual);
    float per_pixel = (ar < 0.01f) ? (50.0f * residual * residual)
                                   : (ar - 0.005f);

    bool m = (rh > 0.5f) && (gmag >= lo) && (gmag <= hi);
    float sel = m ? 1.0f : 0.0f;
    num = fmaf(sel, per_pixel, num);
    den += sel;
}

__device__ __forceinline__ int clampy(int v) {
    return v < 0 ? 0 : (v > H_ - 1 ? H_ - 1 : v);
}

__global__ __launch_bounds__(256, 2) void eikonal_main(
        const float* __restrict__ pred, const float* __restrict__ reach,
        double2* __restrict__ partials) {
    const float target = 1.0f / sqrtf((float)(511 * 511 + 511 * 511));
    const float lo = 0.3f * target;
    const float hi = 5.0f * target;

    int t = threadIdx.x;
    int lane = t & 63;
    // XCD-bijective swizzle (1024 % 8 == 0): consecutive strips share halo rows
    // -> keep them on the same XCD's L2.
    int bswz = (blockIdx.x & 7) * (NBLK_ / 8) + (blockIdx.x >> 3);
    int wv = bswz * 4 + (t >> 6);          // 0..4095
    int b  = wv >> 7;                      // image
    int r  = wv & 127;
    int s  = r >> 1;                       // strip 0..63
    int h  = r & 1;                        // row half
    int y0 = s * RSTRIP_;
    int x0 = (h << 8) + (lane << 2);       // 4 consecutive px per lane

    const float* base  = pred  + b * HW_ + x0;
    const float* rbase = reach + b * HW_ + x0;
    const float* hbase = pred  + b * HW_;

    bool lane0  = (lane == 0);
    bool lane63 = (lane == 63);
    bool haloL = lane0  && (h == 1);       // needs x = 254,255
    bool haloR = lane63 && (h == 0);       // needs x = 256,257
    bool needs_halo = haloL || haloR;
    int hx = haloL ? 254 : 256;

    // ---- prologue: 6-deep pred rows (y0-2..y0+3), 4-deep halo, 2-deep reach
    float4 pm2 = *(const float4*)(base + (clampy(y0 - 2) << 9));
    float4 pm1 = *(const float4*)(base + (clampy(y0 - 1) << 9));
    float4 p0c = *(const float4*)(base + ((y0    ) << 9));
    float4 pp1 = *(const float4*)(base + ((y0 + 1) << 9));
    float4 pp2 = *(const float4*)(base + ((y0 + 2) << 9));
    float4 pp3 = *(const float4*)(base + ((y0 + 3) << 9));

    float2 h0c = make_float2(0.f, 0.f), h1c = h0c, h2c = h0c, h3c = h0c;
    if (needs_halo) {
        h0c = *(const float2*)(hbase + ((y0    ) << 9) + hx);
        h1c = *(const float2*)(hbase + ((y0 + 1) << 9) + hx);
        h2c = *(const float2*)(hbase + ((y0 + 2) << 9) + hx);
        h3c = *(const float2*)(hbase + ((y0 + 3) << 9) + hx);
    }
    float4 q0 = *(const float4*)(rbase + ((y0    ) << 9));
    float4 q1 = *(const float4*)(rbase + ((y0 + 1) << 9));

    float num = 0.0f, den = 0.0f;

    // r5-style steady pipeline: unconditional clamped prefetches every
    // iteration (tail loads are redundant clamped rows -> L2 hits, cheap),
    // rolled chains renamed by full unroll.
    #pragma unroll
    for (int i = 0; i < RSTRIP_; ++i) {
        int y = y0 + i;
        float4 pnew = *(const float4*)(base + (clampy(y + 4) << 9));
        float2 hnew = h3c;
        if (needs_halo) hnew = *(const float2*)(hbase + (clampy(y + 4) << 9) + hx);
        int yq = y + 2 > H_ - 1 ? H_ - 1 : y + 2;
        float4 qnew = *(const float4*)(rbase + (yq << 9));

        // x-neighbors via cross-lane shuffle
        float lz = __shfl_up(p0c.z, 1);     // x0-2
        float lw = __shfl_up(p0c.w, 1);     // x0-1
        float rx = __shfl_down(p0c.x, 1);   // x0+4
        float ry = __shfl_down(p0c.y, 1);   // x0+5
        if (lane0)  { lz = (h == 1) ? h0c.x : p0c.x; lw = (h == 1) ? h0c.y : p0c.x; }
        if (lane63) { rx = (h == 0) ? h0c.x : p0c.w; ry = (h == 0) ? h0c.y : p0c.w; }

        float dx0 = lw    - lz;
        float dx1 = p0c.x - lw;
        float dx2 = p0c.y - p0c.x;
        float dx3 = p0c.z - p0c.y;
        float dx4 = p0c.w - p0c.z;
        float dx5 = rx    - p0c.w;
        float dx6 = ry    - rx;

        pixel_eval(dx0, dx1, dx2, dx3,
                   pm1.x - pm2.x, p0c.x - pm1.x, pp1.x - p0c.x, pp2.x - pp1.x,
                   q0.x, target, lo, hi, num, den);
        pixel_eval(dx1, dx2, dx3, dx4,
                   pm1.y - pm2.y, p0c.y - pm1.y, pp1.y - p0c.y, pp2.y - pp1.y,
                   q0.y, target, lo, hi, num, den);
        pixel_eval(dx2, dx3, dx4, dx5,
                   pm1.z - pm2.z, p0c.z - pm1.z, pp1.z - p0c.z, pp2.z - pp1.z,
                   q0.z, target, lo, hi, num, den);
        pixel_eval(dx3, dx4, dx5, dx6,
                   pm1.w - pm2.w, p0c.w - pm1.w, pp1.w - p0c.w, pp2.w - pp1.w,
                   q0.w, target, lo, hi, num, den);

        // roll chains (renamed by unroll)
        pm2 = pm1; pm1 = p0c; p0c = pp1; pp1 = pp2; pp2 = pp3; pp3 = pnew;
        h0c = h1c; h1c = h2c; h2c = h3c; h3c = hnew;
        q0 = q1; q1 = qnew;
    }

    // ---- block reduction ----
    double dn = (double)num;
    double dd = (double)den;
    #pragma unroll
    for (int off = 32; off > 0; off >>= 1) {
        dn += __shfl_down(dn, off);
        dd += __shfl_down(dd, off);
    }
    __shared__ double sn[4], sd[4];
    int wid = t >> 6;
    if (lane == 0) { sn[wid] = dn; sd[wid] = dd; }
    __syncthreads();
    if (t == 0) {
        double2 p;
        p.x = sn[0] + sn[1] + sn[2] + sn[3];
        p.y = sd[0] + sd[1] + sd[2] + sd[3];
        partials[blockIdx.x] = p;
    }
}

__global__ __launch_bounds__(256) void eikonal_finalize(
        const double2* __restrict__ partials, float* __restrict__ out) {
    int t = threadIdx.x;
    double n = 0.0, d = 0.0;
    #pragma unroll
    for (int k = 0; k < NBLK_ / 256; ++k) {
        double2 p = partials[t + (k << 8)];
        n += p.x;
        d += p.y;
    }
    #pragma unroll
    for (int off = 32; off > 0; off >>= 1) {
        n += __shfl_down(n, off);
        d += __shfl_down(d, off);
    }
    __shared__ double sn[4], sd[4];
    int wid = t >> 6;
    int lane = t & 63;
    if (lane == 0) { sn[wid] = n; sd[wid] = d; }
    __syncthreads();
    if (t == 0) {
        double num = sn[0] + sn[1] + sn[2] + sn[3];
        double den = sd[0] + sd[1] + sd[2] + sd[3];
        if (den < 1e-8) den = 1e-8;
        out[0] = (float)(num / den);
    }
}

extern "C" void kernel_launch(void* const* d_in, const int* in_sizes, int n_in,
                              void* d_out, int out_size, void* d_ws, size_t ws_size,
                              hipStream_t stream) {
    const float* pred  = (const float*)d_in[0];
    const float* reach = (const float*)d_in[1];
    float* out = (float*)d_out;
    double2* partials = (double2*)d_ws;   // 1024 * 16B = 16 KB, fully rewritten each call

    eikonal_main<<<NBLK_, 256, 0, stream>>>(pred, reach, partials);
    eikonal_finalize<<<1, 256, 0, stream>>>(partials, out);
}

// Round 8
// 35.744 us; speedup vs baseline: 1.2346x; 1.0267x over previous
//
#include <hip/hip_runtime.h>

#define B_  32
#define H_  512
#define W_  512
#define HW_ (H_ * W_)
#define NBLK_ 2048             // 2048 blocks * 8 waves = 16384 waves = 32 img * 512 rows
#define TPB_  512

__device__ __forceinline__ float rcp_fast(float x) { return __builtin_amdgcn_rcpf(x); }

// WENO3, single fast-rcp form (validated rounds 1-7, absmax 0.0)
__device__ __forceinline__ float weno_minus(float vmm, float vm, float vp) {
    float d0 = vmm - vm, d1 = vm - vp;
    float t0 = 1e-6f + d0 * d0;
    float t1 = 1e-6f + d1 * d1;
    float s0 = t0 * t0, s1 = t1 * t1;
    float s0x2 = s0 + s0;
    float p0 = 1.5f * vm - 0.5f * vmm;
    float p1 = 0.5f * (vm + vp);
    return (s1 * p0 + s0x2 * p1) * rcp_fast(s1 + s0x2);
}

__device__ __forceinline__ float weno_plus(float vmm, float vm, float vp) {
    float d0 = vp - vm, d1 = vm - vmm;
    float t0 = 1e-6f + d0 * d0;
    float t1 = 1e-6f + d1 * d1;
    float s0 = t0 * t0, s1 = t1 * t1;
    float s0x2 = s0 + s0;
    float p0 = 1.5f * vm - 0.5f * vp;
    float p1 = 0.5f * (vm + vmm);
    return (s1 * p0 + s0x2 * p1) * rcp_fast(s1 + s0x2);
}

__device__ __forceinline__ void pixel_eval(
        float vxmm, float vxm, float vxc, float vxp,
        float vymm, float vym, float vyc, float vyp,
        float rh, float target, float lo, float hi,
        float& num, float& den) {
    float ux_minus = weno_minus(vxmm, vxm, vxc);
    float ux_plus  = weno_plus(vxm, vxc, vxp);
    float gx = fmaxf(fmaxf(ux_minus, -ux_plus), 0.0f);

    float uy_minus = weno_minus(vymm, vym, vyc);
    float uy_plus  = weno_plus(vym, vyc, vyp);
    float gy = fmaxf(fmaxf(uy_minus, -uy_plus), 0.0f);

    float gmag = __builtin_amdgcn_sqrtf(gx * gx + gy * gy + 1e-8f);

    float residual = gmag - target;
    float ar = fabsf(residual);
    float per_pixel = (ar < 0.01f) ? (50.0f * residual * residual)
                                   : (ar - 0.005f);

    bool m = (rh > 0.5f) && (gmag >= lo) && (gmag <= hi);
    float sel = m ? 1.0f : 0.0f;
    num = fmaf(sel, per_pixel, num);
    den += sel;
}

__device__ __forceinline__ int clampy(int v) {
    return v < 0 ? 0 : (v > H_ - 1 ? H_ - 1 : v);
}

__global__ __launch_bounds__(TPB_) void eikonal_main(
        const float* __restrict__ pred, const float* __restrict__ reach,
        double2* __restrict__ partials) {
    const float target = 1.0f / sqrtf((float)(511 * 511 + 511 * 511));
    const float lo = 0.3f * target;
    const float hi = 5.0f * target;

    int t = threadIdx.x;
    int lane = t & 63;

    // XCD-bijective swizzle (2048 % 8 == 0): consecutive row-groups (which
    // share halo rows) stay on the same XCD's L2.
    int bswz = ((blockIdx.x & 7) << 8) + (blockIdx.x >> 3);
    // wave id, made explicitly wave-uniform so all row addressing is SALU
    int wv = __builtin_amdgcn_readfirstlane((bswz << 3) + (t >> 6)); // 0..16383
    int b = wv >> 9;            // image
    int y = wv & (H_ - 1);      // row

    const float* brow = pred + b * HW_;
    const float* r0p  = brow + (y << 9);
    const float* rm1p = brow + (clampy(y - 1) << 9);
    const float* rm2p = brow + (clampy(y - 2) << 9);
    const float* rp1p = brow + (clampy(y + 1) << 9);
    const float* rp2p = brow + (clampy(y + 2) << 9);
    const float* rrp  = reach + b * HW_ + (y << 9);

    int x0 = lane << 3;         // 8 px per lane

    // ---- issue all 12 independent loads up front ----
    float4 cA  = *(const float4*)(r0p  + x0);
    float4 cB  = *(const float4*)(r0p  + x0 + 4);
    float4 m2A = *(const float4*)(rm2p + x0);
    float4 m2B = *(const float4*)(rm2p + x0 + 4);
    float4 m1A = *(const float4*)(rm1p + x0);
    float4 m1B = *(const float4*)(rm1p + x0 + 4);
    float4 p1A = *(const float4*)(rp1p + x0);
    float4 p1B = *(const float4*)(rp1p + x0 + 4);
    float4 p2A = *(const float4*)(rp2p + x0);
    float4 p2B = *(const float4*)(rp2p + x0 + 4);
    float4 qA  = *(const float4*)(rrp  + x0);
    float4 qB  = *(const float4*)(rrp  + x0 + 4);

    // ---- x halo via 4 shuffles per row ----
    float xm2 = __shfl_up(cB.z, 1);     // u[x0-2]
    float xm1 = __shfl_up(cB.w, 1);     // u[x0-1]
    float xp1 = __shfl_down(cA.x, 1);   // u[x0+8]
    float xp2 = __shfl_down(cA.y, 1);   // u[x0+9]
    if (lane == 0)  { xm2 = cA.x; xm1 = cA.x; }   // edge clamp x=0
    if (lane == 63) { xp1 = cB.w; xp2 = cB.w; }   // edge clamp x=511

    // ---- 11 shared x forward differences (w[k] = u[x0-2+k]) ----
    float D0  = xm1  - xm2;
    float D1  = cA.x - xm1;
    float D2  = cA.y - cA.x;
    float D3  = cA.z - cA.y;
    float D4  = cA.w - cA.z;
    float D5  = cB.x - cA.w;
    float D6  = cB.y - cB.x;
    float D7  = cB.z - cB.y;
    float D8  = cB.w - cB.z;
    float D9  = xp1  - cB.w;
    float D10 = xp2  - xp1;

    float num = 0.0f, den = 0.0f;

    pixel_eval(D0, D1, D2, D3,
               m1A.x - m2A.x, cA.x - m1A.x, p1A.x - cA.x, p2A.x - p1A.x,
               qA.x, target, lo, hi, num, den);
    pixel_eval(D1, D2, D3, D4,
               m1A.y - m2A.y, cA.y - m1A.y, p1A.y - cA.y, p2A.y - p1A.y,
               qA.y, target, lo, hi, num, den);
    pixel_eval(D2, D3, D4, D5,
               m1A.z - m2A.z, cA.z - m1A.z, p1A.z - cA.z, p2A.z - p1A.z,
               qA.z, target, lo, hi, num, den);
    pixel_eval(D3, D4, D5, D6,
               m1A.w - m2A.w, cA.w - m1A.w, p1A.w - cA.w, p2A.w - p1A.w,
               qA.w, target, lo, hi, num, den);
    pixel_eval(D4, D5, D6, D7,
               m1B.x - m2B.x, cB.x - m1B.x, p1B.x - cB.x, p2B.x - p1B.x,
               qB.x, target, lo, hi, num, den);
    pixel_eval(D5, D6, D7, D8,
               m1B.y - m2B.y, cB.y - m1B.y, p1B.y - cB.y, p2B.y - p1B.y,
               qB.y, target, lo, hi, num, den);
    pixel_eval(D6, D7, D8, D9,
               m1B.z - m2B.z, cB.z - m1B.z, p1B.z - cB.z, p2B.z - p1B.z,
               qB.z, target, lo, hi, num, den);
    pixel_eval(D7, D8, D9, D10,
               m1B.w - m2B.w, cB.w - m1B.w, p1B.w - cB.w, p2B.w - p1B.w,
               qB.w, target, lo, hi, num, den);

    // ---- block reduction (8 waves) ----
    double dn = (double)num;
    double dd = (double)den;
    #pragma unroll
    for (int off = 32; off > 0; off >>= 1) {
        dn += __shfl_down(dn, off);
        dd += __shfl_down(dd, off);
    }
    __shared__ double sn[8], sd[8];
    int wid = t >> 6;
    if (lane == 0) { sn[wid] = dn; sd[wid] = dd; }
    __syncthreads();
    if (t == 0) {
        double2 p;
        p.x = sn[0] + sn[1] + sn[2] + sn[3] + sn[4] + sn[5] + sn[6] + sn[7];
        p.y = sd[0] + sd[1] + sd[2] + sd[3] + sd[4] + sd[5] + sd[6] + sd[7];
        partials[blockIdx.x] = p;
    }
}

__global__ __launch_bounds__(256) void eikonal_finalize(
        const double2* __restrict__ partials, float* __restrict__ out) {
    int t = threadIdx.x;
    double n = 0.0, d = 0.0;
    #pragma unroll
    for (int k = 0; k < NBLK_ / 256; ++k) {
        double2 p = partials[t + (k << 8)];
        n += p.x;
        d += p.y;
    }
    #pragma unroll
    for (int off = 32; off > 0; off >>= 1) {
        n += __shfl_down(n, off);
        d += __shfl_down(d, off);
    }
    __shared__ double sn[4], sd[4];
    int wid = t >> 6;
    int lane = t & 63;
    if (lane == 0) { sn[wid] = n; sd[wid] = d; }
    __syncthreads();
    if (t == 0) {
        double num = sn[0] + sn[1] + sn[2] + sn[3];
        double den = sd[0] + sd[1] + sd[2] + sd[3];
        if (den < 1e-8) den = 1e-8;
        out[0] = (float)(num / den);
    }
}

extern "C" void kernel_launch(void* const* d_in, const int* in_sizes, int n_in,
                              void* d_out, int out_size, void* d_ws, size_t ws_size,
                              hipStream_t stream) {
    const float* pred  = (const float*)d_in[0];
    const float* reach = (const float*)d_in[1];
    float* out = (float*)d_out;
    double2* partials = (double2*)d_ws;   // 2048 * 16B = 32 KB, fully rewritten each call

    eikonal_main<<<NBLK_, TPB_, 0, stream>>>(pred, reach, partials);
    eikonal_finalize<<<1, 256, 0, stream>>>(partials, out);
}

// Round 9
// 31.123 us; speedup vs baseline: 1.4180x; 1.1485x over previous
//
#include <hip/hip_runtime.h>

#define B_  32
#define H_  512
#define W_  512
#define HW_ (H_ * W_)
#define NBLK_ 2048             // 2048 blocks * 4 waves = 8192 waves = 32 img * 256 row-pairs
#define TPB_  256

typedef float f32x4 __attribute__((ext_vector_type(4)));

__device__ __forceinline__ float rcp_fast(float x) { return __builtin_amdgcn_rcpf(x); }

// WENO3, single fast-rcp form (validated rounds 1-8, absmax 0.0)
__device__ __forceinline__ float weno_minus(float vmm, float vm, float vp) {
    float d0 = vmm - vm, d1 = vm - vp;
    float t0 = 1e-6f + d0 * d0;
    float t1 = 1e-6f + d1 * d1;
    float s0 = t0 * t0, s1 = t1 * t1;
    float s0x2 = s0 + s0;
    float p0 = 1.5f * vm - 0.5f * vmm;
    float p1 = 0.5f * (vm + vp);
    return (s1 * p0 + s0x2 * p1) * rcp_fast(s1 + s0x2);
}

__device__ __forceinline__ float weno_plus(float vmm, float vm, float vp) {
    float d0 = vp - vm, d1 = vm - vmm;
    float t0 = 1e-6f + d0 * d0;
    float t1 = 1e-6f + d1 * d1;
    float s0 = t0 * t0, s1 = t1 * t1;
    float s0x2 = s0 + s0;
    float p0 = 1.5f * vm - 0.5f * vp;
    float p1 = 0.5f * (vm + vmm);
    return (s1 * p0 + s0x2 * p1) * rcp_fast(s1 + s0x2);
}

__device__ __forceinline__ void pixel_eval(
        float vxmm, float vxm, float vxc, float vxp,
        float vymm, float vym, float vyc, float vyp,
        float rh, float target, float lo, float hi,
        float& num, float& den) {
    float ux_minus = weno_minus(vxmm, vxm, vxc);
    float ux_plus  = weno_plus(vxm, vxc, vxp);
    float gx = fmaxf(fmaxf(ux_minus, -ux_plus), 0.0f);

    float uy_minus = weno_minus(vymm, vym, vyc);
    float uy_plus  = weno_plus(vym, vyc, vyp);
    float gy = fmaxf(fmaxf(uy_minus, -uy_plus), 0.0f);

    float gmag = __builtin_amdgcn_sqrtf(gx * gx + gy * gy + 1e-8f);

    float residual = gmag - target;
    float ar = fabsf(residual);
    float per_pixel = (ar < 0.01f) ? (50.0f * residual * residual)
                                   : (ar - 0.005f);

    bool m = (rh > 0.5f) && (gmag >= lo) && (gmag <= hi);
    float sel = m ? 1.0f : 0.0f;
    num = fmaf(sel, per_pixel, num);
    den += sel;
}

// One full row (8 px/lane): c=center row, m2/m1/p1/p2 = y-neighbor rows, q = reach.
__device__ __forceinline__ void row_eval(
        f32x4 c0, f32x4 c1,
        f32x4 m2_0, f32x4 m2_1, f32x4 m1_0, f32x4 m1_1,
        f32x4 p1_0, f32x4 p1_1, f32x4 p2_0, f32x4 p2_1,
        f32x4 q0, f32x4 q1,
        int lane, float target, float lo, float hi,
        float& num, float& den) {
    // x halo via 4 shuffles; image-edge clamp from own registers
    float xm2 = __shfl_up(c1.z, 1);
    float xm1 = __shfl_up(c1.w, 1);
    float xp1 = __shfl_down(c0.x, 1);
    float xp2 = __shfl_down(c0.y, 1);
    if (lane == 0)  { xm2 = c0.x; xm1 = c0.x; }
    if (lane == 63) { xp1 = c1.w; xp2 = c1.w; }

    // 11 shared x forward differences
    float D0  = xm1 - xm2;
    float D1  = c0.x - xm1;
    float D2  = c0.y - c0.x;
    float D3  = c0.z - c0.y;
    float D4  = c0.w - c0.z;
    float D5  = c1.x - c0.w;
    float D6  = c1.y - c1.x;
    float D7  = c1.z - c1.y;
    float D8  = c1.w - c1.z;
    float D9  = xp1 - c1.w;
    float D10 = xp2 - xp1;

    pixel_eval(D0, D1, D2, D3,
               m1_0.x - m2_0.x, c0.x - m1_0.x, p1_0.x - c0.x, p2_0.x - p1_0.x,
               q0.x, target, lo, hi, num, den);
    pixel_eval(D1, D2, D3, D4,
               m1_0.y - m2_0.y, c0.y - m1_0.y, p1_0.y - c0.y, p2_0.y - p1_0.y,
               q0.y, target, lo, hi, num, den);
    pixel_eval(D2, D3, D4, D5,
               m1_0.z - m2_0.z, c0.z - m1_0.z, p1_0.z - c0.z, p2_0.z - p1_0.z,
               q0.z, target, lo, hi, num, den);
    pixel_eval(D3, D4, D5, D6,
               m1_0.w - m2_0.w, c0.w - m1_0.w, p1_0.w - c0.w, p2_0.w - p1_0.w,
               q0.w, target, lo, hi, num, den);
    pixel_eval(D4, D5, D6, D7,
               m1_1.x - m2_1.x, c1.x - m1_1.x, p1_1.x - c1.x, p2_1.x - p1_1.x,
               q1.x, target, lo, hi, num, den);
    pixel_eval(D5, D6, D7, D8,
               m1_1.y - m2_1.y, c1.y - m1_1.y, p1_1.y - c1.y, p2_1.y - p1_1.y,
               q1.y, target, lo, hi, num, den);
    pixel_eval(D6, D7, D8, D9,
               m1_1.z - m2_1.z, c1.z - m1_1.z, p1_1.z - c1.z, p2_1.z - p1_1.z,
               q1.z, target, lo, hi, num, den);
    pixel_eval(D7, D8, D9, D10,
               m1_1.w - m2_1.w, c1.w - m1_1.w, p1_1.w - c1.w, p2_1.w - p1_1.w,
               q1.w, target, lo, hi, num, den);
}

__device__ __forceinline__ int clampy(int v) {
    return v < 0 ? 0 : (v > H_ - 1 ? H_ - 1 : v);
}

__global__ __launch_bounds__(TPB_) void eikonal_main(
        const float* __restrict__ pred, const float* __restrict__ reach,
        double2* __restrict__ partials) {
    const float target = 1.0f / sqrtf((float)(511 * 511 + 511 * 511));
    const float lo = 0.3f * target;
    const float hi = 5.0f * target;

    int t = threadIdx.x;
    int lane = t & 63;

    // XCD-bijective swizzle (2048 % 8 == 0): neighboring row-pairs share halo
    // rows -> same XCD L2.
    int bswz = ((blockIdx.x & 7) << 8) + (blockIdx.x >> 3);
    // wave-uniform id -> all row addressing is SALU
    int wv = __builtin_amdgcn_readfirstlane((bswz << 2) + (t >> 6)); // 0..8191
    int b  = wv >> 8;            // image
    int y0 = (wv & 255) << 1;    // even row; wave owns rows y0, y0+1

    const float* brow = pred + b * HW_;
    int x0 = lane << 3;          // 8 px per lane

    const float* rA = brow + (clampy(y0 - 2) << 9) + x0;
    const float* rB = brow + (clampy(y0 - 1) << 9) + x0;
    const float* rC = brow + ((y0    ) << 9) + x0;
    const float* rD = brow + ((y0 + 1) << 9) + x0;
    const float* rE = brow + (clampy(y0 + 2) << 9) + x0;
    const float* rF = brow + (clampy(y0 + 3) << 9) + x0;
    const float* qC = reach + b * HW_ + ((y0    ) << 9) + x0;
    const float* qD = reach + b * HW_ + ((y0 + 1) << 9) + x0;

    // ---- issue all 16 loads ----
    f32x4 pA0 = *(const f32x4*)(rA);     f32x4 pA1 = *(const f32x4*)(rA + 4);
    f32x4 pB0 = *(const f32x4*)(rB);     f32x4 pB1 = *(const f32x4*)(rB + 4);
    f32x4 pC0 = *(const f32x4*)(rC);     f32x4 pC1 = *(const f32x4*)(rC + 4);
    f32x4 pD0 = *(const f32x4*)(rD);     f32x4 pD1 = *(const f32x4*)(rD + 4);
    f32x4 pE0 = *(const f32x4*)(rE);     f32x4 pE1 = *(const f32x4*)(rE + 4);
    f32x4 pF0 = *(const f32x4*)(rF);     f32x4 pF1 = *(const f32x4*)(rF + 4);
    f32x4 qC0 = *(const f32x4*)(qC);     f32x4 qC1 = *(const f32x4*)(qC + 4);
    f32x4 qD0 = *(const f32x4*)(qD);     f32x4 qD1 = *(const f32x4*)(qD + 4);

    // Pin ALL loads live at this point: forces the compiler to issue all 16
    // before a single wait (prevents regalloc from sinking loads to uses).
    asm volatile("" ::
        "v"(pA0), "v"(pA1), "v"(pB0), "v"(pB1),
        "v"(pC0), "v"(pC1), "v"(pD0), "v"(pD1),
        "v"(pE0), "v"(pE1), "v"(pF0), "v"(pF1),
        "v"(qC0), "v"(qC1), "v"(qD0), "v"(qD1));
    __builtin_amdgcn_sched_barrier(0);   // nothing moves across

    float num = 0.0f, den = 0.0f;

    // row C: neighbors A,B | D,E
    row_eval(pC0, pC1, pA0, pA1, pB0, pB1, pD0, pD1, pE0, pE1,
             qC0, qC1, lane, target, lo, hi, num, den);
    // row D: neighbors B,C | E,F
    row_eval(pD0, pD1, pB0, pB1, pC0, pC1, pE0, pE1, pF0, pF1,
             qD0, qD1, lane, target, lo, hi, num, den);

    // ---- block reduction (4 waves) ----
    double dn = (double)num;
    double dd = (double)den;
    #pragma unroll
    for (int off = 32; off > 0; off >>= 1) {
        dn += __shfl_down(dn, off);
        dd += __shfl_down(dd, off);
    }
    __shared__ double sn[4], sd[4];
    int wid = t >> 6;
    if (lane == 0) { sn[wid] = dn; sd[wid] = dd; }
    __syncthreads();
    if (t == 0) {
        double2 p;
        p.x = sn[0] + sn[1] + sn[2] + sn[3];
        p.y = sd[0] + sd[1] + sd[2] + sd[3];
        partials[blockIdx.x] = p;
    }
}

__global__ __launch_bounds__(256) void eikonal_finalize(
        const double2* __restrict__ partials, float* __restrict__ out) {
    int t = threadIdx.x;
    double n = 0.0, d = 0.0;
    #pragma unroll
    for (int k = 0; k < NBLK_ / 256; ++k) {
        double2 p = partials[t + (k << 8)];
        n += p.x;
        d += p.y;
    }
    #pragma unroll
    for (int off = 32; off > 0; off >>= 1) {
        n += __shfl_down(n, off);
        d += __shfl_down(d, off);
    }
    __shared__ double sn[4], sd[4];
    int wid = t >> 6;
    int lane = t & 63;
    if (lane == 0) { sn[wid] = n; sd[wid] = d; }
    __syncthreads();
    if (t == 0) {
        double num = sn[0] + sn[1] + sn[2] + sn[3];
        double den = sd[0] + sd[1] + sd[2] + sd[3];
        if (den < 1e-8) den = 1e-8;
        out[0] = (float)(num / den);
    }
}

extern "C" void kernel_launch(void* const* d_in, const int* in_sizes, int n_in,
                              void* d_out, int out_size, void* d_ws, size_t ws_size,
                              hipStream_t stream) {
    const float* pred  = (const float*)d_in[0];
    const float* reach = (const float*)d_in[1];
    float* out = (float*)d_out;
    double2* partials = (double2*)d_ws;   // 2048 * 16B = 32 KB, fully rewritten each call

    eikonal_main<<<NBLK_, TPB_, 0, stream>>>(pred, reach, partials);
    eikonal_finalize<<<1, 256, 0, stream>>>(partials, out);
}